// Round 6
// baseline (307.318 us; speedup 1.0000x reference)
//
#include <hip/hip_runtime.h>

#define K_NEIGH 32
#define D_FEAT  128

__device__ __forceinline__ float readlane_f(float v, int l) {
    return __int_as_float(__builtin_amdgcn_readlane(__float_as_int(v), l));
}

// One wave per batch element. Lane l owns dims {2l, 2l+1} (float2).
// Phase 1: 32 independent coalesced row loads, consumed into dot/norm
// partials on arrival (nothing kept). Reduction: 6-step fold (lane l ends
// holding sim of row l>>1). Top-k rank in fp32, bit-exact vs lax.top_k.
// Phase 2: re-gather ONLY the ns selected rows (scalar indices, 2 loads
// in flight per iteration) — not the compiler-remat 32-row re-gather of R3.
__global__ __launch_bounds__(256, 3) void intra_agg_kernel(
    const float* __restrict__ features,
    const int*   __restrict__ nodes,
    const int*   __restrict__ neighs,
    const int*   __restrict__ num_sample_p,
    float*       __restrict__ out,
    int batch)
{
    const int tid  = blockIdx.x * blockDim.x + threadIdx.x;
    const int lane = threadIdx.x & 63;
    int b = tid >> 6;
    if (b >= batch) return;
    b = __builtin_amdgcn_readfirstlane(b);   // scalar index/address path

    const int  ns = *num_sample_p;
    const int* nb = neighs + (size_t)b * K_NEIGH;

    // Center fragment (coalesced 512B) + ||center|| (6-step butterfly).
    const int    cnode = nodes[b];
    const float2 c2 = ((const float2*)(features + (size_t)cnode * D_FEAT))[lane];
    float cc = c2.x * c2.x + c2.y * c2.y;
    #pragma unroll
    for (int m = 32; m >= 1; m >>= 1) cc += __shfl_xor(cc, m);
    const float cn = sqrtf(cc);

    // 32 rows: independent coalesced loads, consumed into partials.
    float dt[K_NEIGH], n2[K_NEIGH];
    #pragma unroll
    for (int r = 0; r < K_NEIGH; ++r) {
        const int    nidx = nb[r];           // wave-uniform -> s_load
        const float2 v = ((const float2*)(features + (size_t)nidx * D_FEAT))[lane];
        dt[r] = c2.x * v.x + c2.y * v.y;
        n2[r] = v.x * v.x + v.y * v.y;
    }

    // Fold: halves values-per-lane and lanes-per-value each step.
    #pragma unroll
    for (int o = 32; o >= 2; o >>= 1) {
        const bool up = (lane & o) != 0;
        #pragma unroll
        for (int r = 0; r < o / 2; ++r) {
            const float sd = up ? dt[r] : dt[r + o / 2];
            const float sn = up ? n2[r] : n2[r + o / 2];
            const float rd = __shfl_xor(sd, o);
            const float rn = __shfl_xor(sn, o);
            const float kd = up ? dt[r + o / 2] : dt[r];
            const float kn = up ? n2[r + o / 2] : n2[r];
            dt[r] = kd + rd;
            n2[r] = kn + rn;
        }
    }
    dt[0] += __shfl_xor(dt[0], 1);
    n2[0] += __shfl_xor(n2[0], 1);

    const int   myrow = lane >> 1;           // row whose sim this lane holds
    const float sim   = dt[0] / (cn * sqrtf(n2[0]));

    // Stable rank (matches lax.top_k tie-breaking): row j lives at lane 2j.
    int rank = 0;
    #pragma unroll
    for (int j = 0; j < K_NEIGH; ++j) {
        const float sj = readlane_f(sim, 2 * j);
        rank += (sj > sim || (sj == sim && j < myrow)) ? 1 : 0;
    }

    // Ballot has row j's bit duplicated at 2j,2j+1 -> compress even bits.
    const unsigned long long bal = __ballot(rank < ns);
    unsigned long long x = bal & 0x5555555555555555ull;
    x = (x | (x >> 1))  & 0x3333333333333333ull;
    x = (x | (x >> 2))  & 0x0F0F0F0F0F0F0F0Full;
    x = (x | (x >> 4))  & 0x00FF00FF00FF00FFull;
    x = (x | (x >> 8))  & 0x0000FFFF0000FFFFull;
    x = (x | (x >> 16)) & 0x00000000FFFFFFFFull;
    unsigned mask = __builtin_amdgcn_readfirstlane((unsigned)x);

    // Phase 2: mean over ONLY the selected rows (uniform scalar bit-scan,
    // two independent loads in flight per iteration).
    float2 acc = make_float2(0.f, 0.f);
    while (mask) {
        const int j0 = __ffs(mask) - 1; mask &= mask - 1;
        const float2* p0 = (const float2*)(features + (size_t)nb[j0] * D_FEAT);
        if (mask) {
            const int j1 = __ffs(mask) - 1; mask &= mask - 1;
            const float2* p1 = (const float2*)(features + (size_t)nb[j1] * D_FEAT);
            const float2 v0 = p0[lane];
            const float2 v1 = p1[lane];
            acc.x += v0.x + v1.x;
            acc.y += v0.y + v1.y;
        } else {
            const float2 v0 = p0[lane];
            acc.x += v0.x;
            acc.y += v0.y;
        }
    }
    const float nsf = (float)ns;
    float2 ov;
    ov.x = fmaxf(acc.x / nsf, 0.f);
    ov.y = fmaxf(acc.y / nsf, 0.f);
    ((float2*)(out + (size_t)b * D_FEAT))[lane] = ov;
}

extern "C" void kernel_launch(void* const* d_in, const int* in_sizes, int n_in,
                              void* d_out, int out_size, void* d_ws, size_t ws_size,
                              hipStream_t stream) {
    const float* features = (const float*)d_in[0];
    const int*   nodes    = (const int*)d_in[1];
    const int*   neighs   = (const int*)d_in[2];
    const int*   ns       = (const int*)d_in[3];
    float*       out      = (float*)d_out;

    const int batch  = in_sizes[1];            // 32768
    const int blocks = (batch + 3) / 4;        // 4 waves per 256-thread block

    intra_agg_kernel<<<blocks, 256, 0, stream>>>(features, nodes, neighs, ns, out, batch);
}

// Round 7
// 163.935 us; speedup vs baseline: 1.8746x; 1.8746x over previous
//
#include <hip/hip_runtime.h>

#define K_NEIGH 32
#define D_FEAT  128

__device__ __forceinline__ float readlane_f(float v, int l) {
    return __int_as_float(__builtin_amdgcn_readlane(__float_as_int(v), l));
}

// One wave per batch element. Lane l owns dims [4*l32, 4*l32+4) (float4);
// lower half-wave owns rows 0..15, upper half rows 16..31 -> 16 load
// instructions (1KB each) cover all 32 rows once. Rows are PINNED in VGPRs
// via empty asm so the compiler cannot rematerialize the gather in the mean
// phase (R3's hidden 2x cost). Fold reduction within each 32-lane half;
// top-k rank in fp32 (bit-exact vs lax.top_k); mean = predicated FMA from
// registers (zero loads). launch_bounds(256,3): ~170 VGPR cap, no spills.
__global__ __launch_bounds__(256, 3) void intra_agg_kernel(
    const float* __restrict__ features,
    const int*   __restrict__ nodes,
    const int*   __restrict__ neighs,
    const int*   __restrict__ num_sample_p,
    float*       __restrict__ out,
    int batch)
{
    const int tid  = blockIdx.x * blockDim.x + threadIdx.x;
    const int lane = threadIdx.x & 63;
    const int l32  = lane & 31;
    const int half = lane >> 5;
    int b = tid >> 6;
    if (b >= batch) return;
    b = __builtin_amdgcn_readfirstlane(b);   // scalar index/address path

    const int  ns = *num_sample_p;
    const int* nb = neighs + (size_t)b * K_NEIGH;

    // Center fragment + ||center|| (5-step butterfly within each half).
    const int    cnode = nodes[b];
    const float4 c4 = ((const float4*)(features + (size_t)cnode * D_FEAT))[l32];
    float cc = c4.x*c4.x + c4.y*c4.y + c4.z*c4.z + c4.w*c4.w;
    #pragma unroll
    for (int m = 16; m >= 1; m >>= 1) cc += __shfl_xor(cc, m);
    const float cn = sqrtf(cc);

    // 16 independent 1KB loads cover all 32 rows; consume into partials and
    // pin the row data in registers for the mean phase.
    float4 rows[16];
    float  dt[16], n2[16];
    #pragma unroll
    for (int i = 0; i < 16; ++i) {
        const int ilo  = nb[i];          // SGPR (uniform)
        const int ihi  = nb[16 + i];     // SGPR (uniform)
        const int nidx = half ? ihi : ilo;   // one v_cndmask per row
        float4 v = ((const float4*)(features + (size_t)nidx * D_FEAT))[l32];
        asm volatile("" : "+v"(v.x), "+v"(v.y), "+v"(v.z), "+v"(v.w));
        rows[i] = v;
        dt[i] = c4.x*v.x + c4.y*v.y + c4.z*v.z + c4.w*v.w;
        n2[i] =  v.x*v.x +  v.y*v.y +  v.z*v.z +  v.w*v.w;
    }

    // Fold within each 32-lane half: 16 values -> lane l32 holds its half's
    // row (l32>>1) after the final xor-1 step. (Verified in R5.)
    #pragma unroll
    for (int o = 16; o >= 2; o >>= 1) {
        const bool up = (lane & o) != 0;
        #pragma unroll
        for (int r = 0; r < o / 2; ++r) {
            const float sd = up ? dt[r] : dt[r + o / 2];
            const float sn = up ? n2[r] : n2[r + o / 2];
            const float rd = __shfl_xor(sd, o);
            const float rn = __shfl_xor(sn, o);
            const float kd = up ? dt[r + o / 2] : dt[r];
            const float kn = up ? n2[r + o / 2] : n2[r];
            dt[r] = kd + rd;
            n2[r] = kn + rn;
        }
    }
    dt[0] += __shfl_xor(dt[0], 1);
    n2[0] += __shfl_xor(n2[0], 1);

    const int   myrow = (half << 4) | (l32 >> 1);   // global row this lane holds
    const float sim   = dt[0] / (cn * sqrtf(n2[0]));

    // Stable rank (matches lax.top_k): row j's sim lives at lane 2j, all j.
    int rank = 0;
    #pragma unroll
    for (int j = 0; j < K_NEIGH; ++j) {
        const float sj = readlane_f(sim, 2 * j);
        rank += (sj > sim || (sj == sim && j < myrow)) ? 1 : 0;
    }

    // Ballot has row j's bit duplicated at 2j,2j+1 -> compress even bits.
    const unsigned long long bal = __ballot(rank < ns);
    unsigned long long x = bal & 0x5555555555555555ull;
    x = (x | (x >> 1))  & 0x3333333333333333ull;
    x = (x | (x >> 2))  & 0x0F0F0F0F0F0F0F0Full;
    x = (x | (x >> 4))  & 0x00FF00FF00FF00FFull;
    x = (x | (x >> 8))  & 0x0000FFFF0000FFFFull;
    x = (x | (x >> 16)) & 0x00000000FFFFFFFFull;
    const unsigned mask = (unsigned)x;               // bit j = row j selected
    const unsigned hm   = (mask >> (half ? 16 : 0)) & 0xffffu;  // this half's rows

    // Mean from pinned registers: predicated FMA, zero loads, no divergence.
    float4 acc = make_float4(0.f, 0.f, 0.f, 0.f);
    #pragma unroll
    for (int i = 0; i < 16; ++i) {
        const float w = (float)((hm >> i) & 1u);
        acc.x = fmaf(rows[i].x, w, acc.x);
        acc.y = fmaf(rows[i].y, w, acc.y);
        acc.z = fmaf(rows[i].z, w, acc.z);
        acc.w = fmaf(rows[i].w, w, acc.w);
    }
    // Combine the two halves' partial sums.
    acc.x += __shfl_xor(acc.x, 32);
    acc.y += __shfl_xor(acc.y, 32);
    acc.z += __shfl_xor(acc.z, 32);
    acc.w += __shfl_xor(acc.w, 32);

    if (half == 0) {
        const float nsf = (float)ns;
        float4 o;
        o.x = fmaxf(acc.x / nsf, 0.f);
        o.y = fmaxf(acc.y / nsf, 0.f);
        o.z = fmaxf(acc.z / nsf, 0.f);
        o.w = fmaxf(acc.w / nsf, 0.f);
        ((float4*)(out + (size_t)b * D_FEAT))[l32] = o;
    }
}

extern "C" void kernel_launch(void* const* d_in, const int* in_sizes, int n_in,
                              void* d_out, int out_size, void* d_ws, size_t ws_size,
                              hipStream_t stream) {
    const float* features = (const float*)d_in[0];
    const int*   nodes    = (const int*)d_in[1];
    const int*   neighs   = (const int*)d_in[2];
    const int*   ns       = (const int*)d_in[3];
    float*       out      = (float*)d_out;

    const int batch  = in_sizes[1];            // 32768
    const int blocks = (batch + 3) / 4;        // 4 waves per 256-thread block

    intra_agg_kernel<<<blocks, 256, 0, stream>>>(features, nodes, neighs, ns, out, batch);
}